// Round 2
// baseline (499.448 us; speedup 1.0000x reference)
//
#include <hip/hip_runtime.h>
#include <hip/hip_bf16.h>

typedef unsigned short u16;
typedef __attribute__((ext_vector_type(8))) short bf16x8;   // 8 bf16 = 4 VGPR
typedef __attribute__((ext_vector_type(4))) float f32x4;    // MFMA 16x16 acc

#define B_ 8
#define S_ 2048
#define H_ 1024
#define M_ (B_ * S_)   // 16384

// ---------- bf16 helpers ----------
__device__ __forceinline__ u16 f2b(float f) {
  __hip_bfloat16 h = __float2bfloat16(f);
  return __builtin_bit_cast(u16, h);
}
__device__ __forceinline__ float b2f(u16 u) {
  __hip_bfloat16 h = __builtin_bit_cast(__hip_bfloat16, u);
  return __bfloat162float(h);
}

// ---------- split fp32 -> bf16 hi/lo (used for W only) ----------
__global__ void split_f32_kernel(const float* __restrict__ x,
                                 u16* __restrict__ hi, u16* __restrict__ lo,
                                 int n4) {
  int stride = gridDim.x * blockDim.x;
  for (int i = blockIdx.x * blockDim.x + threadIdx.x; i < n4; i += stride) {
    float4 v = reinterpret_cast<const float4*>(x)[i];
    ushort4 h, l;
    h.x = f2b(v.x); l.x = f2b(v.x - b2f(h.x));
    h.y = f2b(v.y); l.y = f2b(v.y - b2f(h.y));
    h.z = f2b(v.z); l.z = f2b(v.z - b2f(h.z));
    h.w = f2b(v.w); l.w = f2b(v.w - b2f(h.w));
    reinterpret_cast<ushort4*>(hi)[i] = h;
    reinterpret_cast<ushort4*>(lo)[i] = l;
  }
}

// ---------- transpose X fp32 [b][s][h] -> XT bf16 [b][h][s] ----------
__global__ void transpose_f32_kernel(const float* __restrict__ x,
                                     u16* __restrict__ xt) {
  __shared__ u16 t[64][65];
  int b = blockIdx.z, s0 = blockIdx.x * 64, h0 = blockIdx.y * 64;
  int tx = threadIdx.x, ty = threadIdx.y;
  const float* src = x + ((size_t)b * S_ + s0) * H_ + h0;
#pragma unroll
  for (int i = 0; i < 4; ++i)
    t[ty + 16 * i][tx] = f2b(src[(size_t)(ty + 16 * i) * H_ + tx]);
  __syncthreads();
  u16* dst = xt + ((size_t)b * H_ + h0) * S_ + s0;
#pragma unroll
  for (int i = 0; i < 4; ++i)
    dst[(size_t)(ty + 16 * i) * S_ + tx] = t[tx][ty + 16 * i];
}

// ---------- async global->LDS 16B ----------
__device__ __forceinline__ void async_stage16(const u16* g, u16* l) {
  __builtin_amdgcn_global_load_lds(
      (__attribute__((address_space(1))) void*)g,
      (__attribute__((address_space(3))) void*)l, 16, 0, 0);
}

// Stage a 128x64(bf16) tile (16KB, rows of 128B) from row-major global.
// LDS dest linear; XOR swizzle (byte ^= (row&7)<<4) applied on the *source*
// address (m173 pattern) so swizzled ds_read_b128 is conflict-free.
__device__ __forceinline__ void stage_tile(u16* lds, const u16* g, int ldg,
                                           int wave, int lane) {
#pragma unroll
  for (int r = 0; r < 2; ++r) {
    int c = wave + 8 * r;              // 16 chunks of 1KB, 2 per wave
    int row = c * 8 + (lane >> 3);     // 8 rows per chunk
    int colb = (lane & 7) << 4;        // byte col within 128B row
    int scolb = colb ^ ((row & 7) << 4);
    async_stage16(g + (size_t)row * ldg + (scolb >> 1), lds + c * 512);
  }
}

// Stage a 128x64 fp32 tile, converting to bf16 hi/lo, swizzled LDS writes.
// 512 threads: thread t -> row t>>2, 16 floats at col (t&3)*16.
__device__ __forceinline__ void stage_tile_f32(u16* ldsHi, u16* ldsLo,
                                               const float* g, int ldg,
                                               int tid) {
  int row = tid >> 2;
  int cf = (tid & 3) * 16;  // float col base
  const float* src = g + (size_t)row * ldg + cf;
#pragma unroll
  for (int j = 0; j < 4; ++j) {
    float4 v = reinterpret_cast<const float4*>(src)[j];
    ushort4 h, l;
    h.x = f2b(v.x); l.x = f2b(v.x - b2f(h.x));
    h.y = f2b(v.y); l.y = f2b(v.y - b2f(h.y));
    h.z = f2b(v.z); l.z = f2b(v.z - b2f(h.z));
    h.w = f2b(v.w); l.w = f2b(v.w - b2f(h.w));
    int colb = (cf + j * 4) * 2;  // byte col, 8-aligned
    int off = (row << 7) + (colb ^ ((row & 7) << 4));
    *reinterpret_cast<ushort4*>(reinterpret_cast<char*>(ldsHi) + off) = h;
    *reinterpret_cast<ushort4*>(reinterpret_cast<char*>(ldsLo) + off) = l;
  }
}

// Swizzled fragment read: 8 consecutive bf16 (16B) of tile row `row`.
__device__ __forceinline__ bf16x8 read_frag(const u16* lds, int row, int colb) {
  int off = (row << 7) + (colb ^ ((row & 7) << 4));
  return *reinterpret_cast<const bf16x8*>(
      reinterpret_cast<const char*>(lds) + off);
}

// ---------- BT GEMM: C[m,n] = sum_k A[m,k]*B[n,k] (both k-contiguous) ------
// Operand modes: 0 = bf16 hi only (global_load_lds)
//                1 = bf16 hi+lo   (global_load_lds)
//                2 = fp32, split to hi/lo during reg-staging
// Accumulates hi*hi (+ hi*loB if B has lo) (+ loA*hi if A has lo).
// DUAL_OUT: write C as bf16 hi/lo pair (+bias); else fp32.
template <int AM, int BM, bool DUAL_OUT>
__global__ __launch_bounds__(512) void gemm_kernel(
    const u16* __restrict__ Ahi, const u16* __restrict__ Alo,
    const float* __restrict__ Af,
    const u16* __restrict__ Bhi, const u16* __restrict__ Blo,
    const float* __restrict__ Bf,
    float* __restrict__ Cf, u16* __restrict__ Chi, u16* __restrict__ Clo,
    const float* __restrict__ bias,
    int lda, int ldb, int ldc, int K,
    long sAz, long sBz, long sCz) {
  constexpr int nA = (AM == 0) ? 1 : 2;
  constexpr int nB = (BM == 0) ? 1 : 2;
  __shared__ __align__(16) u16 sA[nA][128 * 64];
  __shared__ __align__(16) u16 sB[nB][128 * 64];

  int tid = threadIdx.x;
  int wave = tid >> 6, lane = tid & 63;
  int wr = wave >> 2, wc = wave & 3;  // 2x4 wave grid; wave tile 64x32
  int bm = blockIdx.x * 128, bn = blockIdx.y * 128;
  long zA = (long)blockIdx.z * sAz;
  long zB = (long)blockIdx.z * sBz;
  long zC = (long)blockIdx.z * sCz;

  const u16* A0 = (AM != 2) ? (Ahi + zA + (size_t)bm * lda) : nullptr;
  const u16* A1 = (AM == 1) ? (Alo + zA + (size_t)bm * lda) : nullptr;
  const float* A2 = (AM == 2) ? (Af + zA + (size_t)bm * lda) : nullptr;
  const u16* B0 = (BM != 2) ? (Bhi + zB + (size_t)bn * ldb) : nullptr;
  const u16* B1 = (BM == 1) ? (Blo + zB + (size_t)bn * ldb) : nullptr;
  const float* B2 = (BM == 2) ? (Bf + zB + (size_t)bn * ldb) : nullptr;

  f32x4 acc[4][2] = {};

  for (int kt = 0; kt < K; kt += 64) {
    __syncthreads();  // protect LDS from previous iteration's readers
    if constexpr (AM == 2) {
      stage_tile_f32(sA[0], sA[1], A2 + kt, lda, tid);
    } else {
      stage_tile(sA[0], A0 + kt, lda, wave, lane);
      if constexpr (AM == 1) stage_tile(sA[1], A1 + kt, lda, wave, lane);
    }
    if constexpr (BM == 2) {
      stage_tile_f32(sB[0], sB[1], B2 + kt, ldb, tid);
    } else {
      stage_tile(sB[0], B0 + kt, ldb, wave, lane);
      if constexpr (BM == 1) stage_tile(sB[1], B1 + kt, ldb, wave, lane);
    }
    __syncthreads();  // drains vmcnt+lgkmcnt (compiler-inserted)

#pragma unroll
    for (int ks = 0; ks < 2; ++ks) {
      int colb = ks * 64 + (lane >> 4) * 16;
      bf16x8 ah[4], bh[2];
#pragma unroll
      for (int m = 0; m < 4; ++m)
        ah[m] = read_frag(sA[0], wr * 64 + m * 16 + (lane & 15), colb);
#pragma unroll
      for (int n = 0; n < 2; ++n)
        bh[n] = read_frag(sB[0], wc * 32 + n * 16 + (lane & 15), colb);
#pragma unroll
      for (int m = 0; m < 4; ++m)
#pragma unroll
        for (int n = 0; n < 2; ++n)
          acc[m][n] = __builtin_amdgcn_mfma_f32_16x16x32_bf16(
              ah[m], bh[n], acc[m][n], 0, 0, 0);
      if constexpr (nB == 2) {
        bf16x8 bl[2];
#pragma unroll
        for (int n = 0; n < 2; ++n)
          bl[n] = read_frag(sB[1], wc * 32 + n * 16 + (lane & 15), colb);
#pragma unroll
        for (int m = 0; m < 4; ++m)
#pragma unroll
          for (int n = 0; n < 2; ++n)
            acc[m][n] = __builtin_amdgcn_mfma_f32_16x16x32_bf16(
                ah[m], bl[n], acc[m][n], 0, 0, 0);
      }
      if constexpr (nA == 2) {
        bf16x8 al[4];
#pragma unroll
        for (int m = 0; m < 4; ++m)
          al[m] = read_frag(sA[1], wr * 64 + m * 16 + (lane & 15), colb);
#pragma unroll
        for (int m = 0; m < 4; ++m)
#pragma unroll
          for (int n = 0; n < 2; ++n)
            acc[m][n] = __builtin_amdgcn_mfma_f32_16x16x32_bf16(
                al[m], bh[n], acc[m][n], 0, 0, 0);
      }
    }
  }

  // Epilogue. C/D layout (verified m89): col = lane&15, row = (lane>>4)*4+reg.
#pragma unroll
  for (int m = 0; m < 4; ++m) {
#pragma unroll
    for (int n = 0; n < 2; ++n) {
#pragma unroll
      for (int r = 0; r < 4; ++r) {
        int row = bm + wr * 64 + m * 16 + (lane >> 4) * 4 + r;
        int col = bn + wc * 32 + n * 16 + (lane & 15);
        float v = acc[m][n][r];
        if constexpr (DUAL_OUT) {
          v += bias[col];
          u16 hv = f2b(v);
          Chi[zC + (size_t)row * ldc + col] = hv;
          Clo[zC + (size_t)row * ldc + col] = f2b(v - b2f(hv));
        } else {
          Cf[zC + (size_t)row * ldc + col] = v;
        }
      }
    }
  }
}

// ---------- row softmax: scores fp32 [rows][2048] -> attn bf16 ----------
__global__ __launch_bounds__(256) void softmax_kernel(const float* __restrict__ sc,
                                                      u16* __restrict__ attn) {
  __shared__ float red[4];
  size_t row = blockIdx.x;
  const float* p = sc + row * S_;
  u16* o = attn + row * S_;
  int t = threadIdx.x;
  float4 v0 = reinterpret_cast<const float4*>(p)[t];
  float4 v1 = reinterpret_cast<const float4*>(p)[t + 256];
  float mx = fmaxf(fmaxf(fmaxf(v0.x, v0.y), fmaxf(v0.z, v0.w)),
                   fmaxf(fmaxf(v1.x, v1.y), fmaxf(v1.z, v1.w)));
#pragma unroll
  for (int d = 32; d > 0; d >>= 1) mx = fmaxf(mx, __shfl_xor(mx, d));
  if ((t & 63) == 0) red[t >> 6] = mx;
  __syncthreads();
  mx = fmaxf(fmaxf(red[0], red[1]), fmaxf(red[2], red[3]));
  float e[8];
  e[0] = __expf(v0.x - mx); e[1] = __expf(v0.y - mx);
  e[2] = __expf(v0.z - mx); e[3] = __expf(v0.w - mx);
  e[4] = __expf(v1.x - mx); e[5] = __expf(v1.y - mx);
  e[6] = __expf(v1.z - mx); e[7] = __expf(v1.w - mx);
  float s = ((e[0] + e[1]) + (e[2] + e[3])) + ((e[4] + e[5]) + (e[6] + e[7]));
#pragma unroll
  for (int d = 32; d > 0; d >>= 1) s += __shfl_xor(s, d);
  __syncthreads();  // everyone done reading red (max phase)
  if ((t & 63) == 0) red[t >> 6] = s;
  __syncthreads();
  s = (red[0] + red[1]) + (red[2] + red[3]);
  float inv = 1.0f / s;
  ushort4 h0, h1;
  h0.x = f2b(e[0] * inv); h0.y = f2b(e[1] * inv);
  h0.z = f2b(e[2] * inv); h0.w = f2b(e[3] * inv);
  h1.x = f2b(e[4] * inv); h1.y = f2b(e[5] * inv);
  h1.z = f2b(e[6] * inv); h1.w = f2b(e[7] * inv);
  reinterpret_cast<ushort4*>(o)[t] = h0;
  reinterpret_cast<ushort4*>(o)[t + 256] = h1;
}

extern "C" void kernel_launch(void* const* d_in, const int* in_sizes, int n_in,
                              void* d_out, int out_size, void* d_ws, size_t ws_size,
                              hipStream_t stream) {
  const float* X = (const float*)d_in[0];     // [8,2048,1024] fp32
  const float* W = (const float*)d_in[1];     // [1024,1024] fp32 (out,in)
  const float* bias = (const float*)d_in[2];  // [1024] fp32
  float* out = (float*)d_out;
  char* ws = (char*)d_ws;

  const size_t MB = 1ull << 20;
  u16* WHI = (u16*)(ws);              // 2MB
  u16* WLO = (u16*)(ws + 2 * MB);     // 2MB
  u16* QWHI = (u16*)(ws + 4 * MB);    // 32MB [16384][1024] bf16
  u16* QWLO = (u16*)(ws + 36 * MB);   // 32MB
  u16* XT = (u16*)(ws + 68 * MB);     // 32MB [b][1024][2048] bf16 (hi)
  // chunked score / attn buffers (CB batches at a time)
  int CB = (ws_size >= 148 * MB) ? 2 : 1;  // peak = 100 + 24*CB MB
  float* SC = (float*)(ws + 100 * MB);               // CB*16MB fp32
  u16* P = (u16*)(ws + 100 * MB + (size_t)CB * 16 * MB);  // CB*8MB bf16

  // 1) W -> hi/lo bf16
  split_f32_kernel<<<512, 256, 0, stream>>>(W, WHI, WLO, H_ * H_ / 4);
  // 2) XT[b][h][s] = bf16(X[b][s][h])  (V operand for PV gemm)
  transpose_f32_kernel<<<dim3(S_ / 64, H_ / 64, B_), dim3(64, 16), 0, stream>>>(X, XT);
  // 3) QW = X @ W^T + b : A=f32(X) split-on-the-fly, B=W hi/lo -> dual bf16 out
  gemm_kernel<2, 1, true><<<dim3(M_ / 128, H_ / 128, 1), 512, 0, stream>>>(
      nullptr, nullptr, X, WHI, WLO, nullptr,
      nullptr, QWHI, QWLO, bias,
      H_, H_, H_, H_, 0, 0, 0);
  // 4-6) per chunk of CB batches: score -> softmax -> PV
  int nch = B_ / CB;
  for (int ch = 0; ch < nch; ++ch) {
    long off = (long)ch * CB;
    // score[z] = QW[z] @ X[z]^T  (A dual bf16, B fp32 split) -> fp32
    gemm_kernel<1, 2, false><<<dim3(S_ / 128, S_ / 128, CB), 512, 0, stream>>>(
        QWHI + off * S_ * H_, QWLO + off * S_ * H_, nullptr,
        nullptr, nullptr, X + off * S_ * H_,
        SC, nullptr, nullptr, nullptr,
        H_, H_, S_, H_, (long)S_ * H_, (long)S_ * H_, (long)S_ * S_);
    // softmax rows -> P bf16
    softmax_kernel<<<CB * S_, 256, 0, stream>>>(SC, P);
    // out[z] = P[z] @ X[z]  (A=P bf16, B=XT bf16) -> fp32
    gemm_kernel<0, 0, false><<<dim3(S_ / 128, H_ / 128, CB), 512, 0, stream>>>(
        P, nullptr, nullptr,
        XT + off * (long)H_ * S_, nullptr, nullptr,
        out + off * (long)S_ * H_, nullptr, nullptr, nullptr,
        S_, S_, H_, S_, (long)S_ * S_, (long)H_ * S_, (long)S_ * H_);
  }
}

// Round 3
// 388.817 us; speedup vs baseline: 1.2845x; 1.2845x over previous
//
#include <hip/hip_runtime.h>
#include <hip/hip_bf16.h>
#include <hip/hip_fp16.h>

typedef unsigned short u16;
typedef __attribute__((ext_vector_type(8))) _Float16 f16x8;  // 8 fp16 = 4 VGPR
typedef __attribute__((ext_vector_type(4))) float f32x4;     // MFMA 16x16 acc

#define B_ 8
#define S_ 2048
#define H_ 1024
#define M_ (B_ * S_)   // 16384

// ---------- fp16 helpers ----------
__device__ __forceinline__ u16 f2h(float f) {
  _Float16 h = (_Float16)f;
  return __builtin_bit_cast(u16, h);
}

// ---------- convert fp32 -> fp16 ----------
__global__ void f32_to_f16_kernel(const float* __restrict__ x,
                                  u16* __restrict__ o, int n4) {
  int stride = gridDim.x * blockDim.x;
  for (int i = blockIdx.x * blockDim.x + threadIdx.x; i < n4; i += stride) {
    float4 v = reinterpret_cast<const float4*>(x)[i];
    ushort4 h;
    h.x = f2h(v.x); h.y = f2h(v.y); h.z = f2h(v.z); h.w = f2h(v.w);
    reinterpret_cast<ushort4*>(o)[i] = h;
  }
}

// ---------- transpose X fp32 [b][s][h] -> XT fp16 [b][h][s] ----------
__global__ void transpose_f32_kernel(const float* __restrict__ x,
                                     u16* __restrict__ xt) {
  __shared__ u16 t[64][65];
  int b = blockIdx.z, s0 = blockIdx.x * 64, h0 = blockIdx.y * 64;
  int tx = threadIdx.x, ty = threadIdx.y;
  const float* src = x + ((size_t)b * S_ + s0) * H_ + h0;
#pragma unroll
  for (int i = 0; i < 4; ++i)
    t[ty + 16 * i][tx] = f2h(src[(size_t)(ty + 16 * i) * H_ + tx]);
  __syncthreads();
  u16* dst = xt + ((size_t)b * H_ + h0) * S_ + s0;
#pragma unroll
  for (int i = 0; i < 4; ++i)
    dst[(size_t)(ty + 16 * i) * S_ + tx] = t[tx][ty + 16 * i];
}

// ---------- async global->LDS 16B ----------
__device__ __forceinline__ void async_stage16(const u16* g, u16* l) {
  __builtin_amdgcn_global_load_lds(
      (__attribute__((address_space(1))) void*)g,
      (__attribute__((address_space(3))) void*)l, 16, 0, 0);
}

// Stage a 128x64(f16) tile (16KB, rows of 128B) from row-major global.
// LDS dest linear; XOR swizzle (byte ^= (row&7)<<4) applied on the *source*
// address (m173 pattern) so swizzled ds_read_b128 is conflict-free.
// 4 waves: each stages 4 chunks of 1KB.
__device__ __forceinline__ void stage_tile(u16* lds, const u16* g, int ldg,
                                           int wave, int lane) {
#pragma unroll
  for (int r = 0; r < 4; ++r) {
    int c = wave + 4 * r;              // 16 chunks of 1KB
    int row = c * 8 + (lane >> 3);     // 8 rows per chunk
    int colb = (lane & 7) << 4;        // byte col within 128B row
    int scolb = colb ^ ((row & 7) << 4);
    async_stage16(g + (size_t)row * ldg + (scolb >> 1), lds + c * 512);
  }
}

// Swizzled fragment read: 8 consecutive f16 (16B) of tile row `row`.
__device__ __forceinline__ f16x8 read_frag(const u16* lds, int row, int colb) {
  int off = (row << 7) + (colb ^ ((row & 7) << 4));
  return *reinterpret_cast<const f16x8*>(
      reinterpret_cast<const char*>(lds) + off);
}

// ---------- BT GEMM: C[m,n] = sum_k A[m,k]*B[n,k] (both fp16, k-contig) ----
// m97 geometry: 256 thr / 4 waves (2x2), wave tile 64x64, acc 4x4, BK=64.
// OM: 0 = fp32 C out, 1 = fp16 C out (+bias).
template <int OM>
__global__ __launch_bounds__(256) void gemm_kernel(
    const u16* __restrict__ A, const u16* __restrict__ B,
    float* __restrict__ Cf, u16* __restrict__ Ch,
    const float* __restrict__ bias,
    int lda, int ldb, int ldc, int K,
    long sAz, long sBz, long sCz) {
  __shared__ __align__(16) u16 sA[128 * 64];
  __shared__ __align__(16) u16 sB[128 * 64];

  int tid = threadIdx.x;
  int wave = tid >> 6, lane = tid & 63;
  int wr = wave >> 1, wc = wave & 1;  // 2x2 wave grid; wave tile 64x64
  int bm = blockIdx.x * 128, bn = blockIdx.y * 128;
  long zA = (long)blockIdx.z * sAz;
  long zB = (long)blockIdx.z * sBz;
  long zC = (long)blockIdx.z * sCz;

  const u16* A0 = A + zA + (size_t)bm * lda;
  const u16* B0 = B + zB + (size_t)bn * ldb;

  f32x4 acc[4][4] = {};

  for (int kt = 0; kt < K; kt += 64) {
    __syncthreads();  // protect LDS from previous iteration's readers
    stage_tile(sA, A0 + kt, lda, wave, lane);
    stage_tile(sB, B0 + kt, ldb, wave, lane);
    __syncthreads();  // compiler drains vmcnt before barrier

#pragma unroll
    for (int ks = 0; ks < 2; ++ks) {
      int colb = ks * 64 + (lane >> 4) * 16;
      f16x8 a[4], b[4];
#pragma unroll
      for (int m = 0; m < 4; ++m)
        a[m] = read_frag(sA, wr * 64 + m * 16 + (lane & 15), colb);
#pragma unroll
      for (int n = 0; n < 4; ++n)
        b[n] = read_frag(sB, wc * 64 + n * 16 + (lane & 15), colb);
#pragma unroll
      for (int m = 0; m < 4; ++m)
#pragma unroll
        for (int n = 0; n < 4; ++n)
          acc[m][n] = __builtin_amdgcn_mfma_f32_16x16x32_f16(
              a[m], b[n], acc[m][n], 0, 0, 0);
    }
  }

  // Epilogue. C/D layout (verified m89): col = lane&15, row = (lane>>4)*4+reg.
#pragma unroll
  for (int m = 0; m < 4; ++m) {
#pragma unroll
    for (int n = 0; n < 4; ++n) {
#pragma unroll
      for (int r = 0; r < 4; ++r) {
        int row = bm + wr * 64 + m * 16 + (lane >> 4) * 4 + r;
        int col = bn + wc * 64 + n * 16 + (lane & 15);
        float v = acc[m][n][r];
        if constexpr (OM == 1) {
          Ch[zC + (size_t)row * ldc + col] = f2h(v + bias[col]);
        } else {
          Cf[zC + (size_t)row * ldc + col] = v;
        }
      }
    }
  }
}

// ---------- row softmax: scores fp32 [rows][2048] -> attn fp16 ----------
__global__ __launch_bounds__(256) void softmax_kernel(const float* __restrict__ sc,
                                                      u16* __restrict__ attn) {
  __shared__ float red[4];
  size_t row = blockIdx.x;
  const float* p = sc + row * S_;
  u16* o = attn + row * S_;
  int t = threadIdx.x;
  float4 v0 = reinterpret_cast<const float4*>(p)[t];
  float4 v1 = reinterpret_cast<const float4*>(p)[t + 256];
  float mx = fmaxf(fmaxf(fmaxf(v0.x, v0.y), fmaxf(v0.z, v0.w)),
                   fmaxf(fmaxf(v1.x, v1.y), fmaxf(v1.z, v1.w)));
#pragma unroll
  for (int d = 32; d > 0; d >>= 1) mx = fmaxf(mx, __shfl_xor(mx, d));
  if ((t & 63) == 0) red[t >> 6] = mx;
  __syncthreads();
  mx = fmaxf(fmaxf(red[0], red[1]), fmaxf(red[2], red[3]));
  float e[8];
  e[0] = __expf(v0.x - mx); e[1] = __expf(v0.y - mx);
  e[2] = __expf(v0.z - mx); e[3] = __expf(v0.w - mx);
  e[4] = __expf(v1.x - mx); e[5] = __expf(v1.y - mx);
  e[6] = __expf(v1.z - mx); e[7] = __expf(v1.w - mx);
  float s = ((e[0] + e[1]) + (e[2] + e[3])) + ((e[4] + e[5]) + (e[6] + e[7]));
#pragma unroll
  for (int d = 32; d > 0; d >>= 1) s += __shfl_xor(s, d);
  __syncthreads();  // everyone done reading red (max phase)
  if ((t & 63) == 0) red[t >> 6] = s;
  __syncthreads();
  s = (red[0] + red[1]) + (red[2] + red[3]);
  float inv = 1.0f / s;
  ushort4 h0, h1;
  h0.x = f2h(e[0] * inv); h0.y = f2h(e[1] * inv);
  h0.z = f2h(e[2] * inv); h0.w = f2h(e[3] * inv);
  h1.x = f2h(e[4] * inv); h1.y = f2h(e[5] * inv);
  h1.z = f2h(e[6] * inv); h1.w = f2h(e[7] * inv);
  reinterpret_cast<ushort4*>(o)[t] = h0;
  reinterpret_cast<ushort4*>(o)[t + 256] = h1;
}

extern "C" void kernel_launch(void* const* d_in, const int* in_sizes, int n_in,
                              void* d_out, int out_size, void* d_ws, size_t ws_size,
                              hipStream_t stream) {
  const float* X = (const float*)d_in[0];     // [8,2048,1024] fp32
  const float* W = (const float*)d_in[1];     // [1024,1024] fp32 (out,in)
  const float* bias = (const float*)d_in[2];  // [1024] fp32
  float* out = (float*)d_out;
  char* ws = (char*)d_ws;

  const size_t MB = 1ull << 20;
  u16* XF = (u16*)(ws);               // 32MB [16384][1024] fp16
  u16* WF = (u16*)(ws + 32 * MB);     // 2MB  [1024][1024] fp16
  u16* XT = (u16*)(ws + 34 * MB);     // 32MB [b][1024][2048] fp16
  u16* QW = (u16*)(ws + 66 * MB);     // 32MB [16384][1024] fp16
  float* SC = (float*)(ws + 98 * MB); // 32MB [2][2048][2048] fp32 (chunked)
  u16* P = (u16*)(ws + 130 * MB);     // 16MB [2][2048][2048] fp16 (chunked)
  const int CB = 2;                   // batches per chunk; peak ws = 146MB

  // 1) X, W -> fp16
  f32_to_f16_kernel<<<2048, 256, 0, stream>>>(X, XF, M_ * H_ / 4);
  f32_to_f16_kernel<<<1024, 256, 0, stream>>>(W, WF, H_ * H_ / 4);
  // 2) XT[b][h][s] = fp16(X[b][s][h])  (V operand for PV gemm)
  transpose_f32_kernel<<<dim3(S_ / 64, H_ / 64, B_), dim3(64, 16), 0, stream>>>(X, XT);
  // 3) QW = X @ W^T + b  -> fp16
  gemm_kernel<1><<<dim3(M_ / 128, H_ / 128, 1), 256, 0, stream>>>(
      XF, WF, nullptr, QW, bias, H_, H_, H_, H_, 0, 0, 0);
  // 4-6) per chunk of CB batches: score -> softmax -> PV
  for (int ch = 0; ch < B_ / CB; ++ch) {
    long off = (long)ch * CB;
    // score[z] = QW[z] @ X[z]^T -> fp32
    gemm_kernel<0><<<dim3(S_ / 128, S_ / 128, CB), 256, 0, stream>>>(
        QW + off * S_ * H_, XF + off * S_ * H_, SC, nullptr, nullptr,
        H_, H_, S_, H_, (long)S_ * H_, (long)S_ * H_, (long)S_ * S_);
    // softmax rows -> P fp16
    softmax_kernel<<<CB * S_, 256, 0, stream>>>(SC, P);
    // out[z] = P[z] @ X[z]  (via XT) -> fp32
    gemm_kernel<0><<<dim3(S_ / 128, H_ / 128, CB), 256, 0, stream>>>(
        P, XT + off * (long)H_ * S_, out + off * (long)S_ * H_, nullptr, nullptr,
        S_, S_, H_, S_, (long)S_ * S_, (long)H_ * S_, (long)S_ * H_);
  }
}

// Round 4
// 277.141 us; speedup vs baseline: 1.8021x; 1.4030x over previous
//
#include <hip/hip_runtime.h>
#include <hip/hip_bf16.h>
#include <hip/hip_fp16.h>

typedef unsigned short u16;
typedef __attribute__((ext_vector_type(8))) _Float16 f16x8;  // 8 fp16 = 4 VGPR
typedef __attribute__((ext_vector_type(4))) float f32x4;     // MFMA 16x16 acc

#define B_ 8
#define S_ 2048
#define H_ 1024
#define M_ (B_ * S_)   // 16384

__device__ __forceinline__ u16 f2h(float f) {
  _Float16 h = (_Float16)f;
  return __builtin_bit_cast(u16, h);
}

// ---------- convert fp32 -> fp16 ----------
__global__ void f32_to_f16_kernel(const float* __restrict__ x,
                                  u16* __restrict__ o, int n4) {
  int stride = gridDim.x * blockDim.x;
  for (int i = blockIdx.x * blockDim.x + threadIdx.x; i < n4; i += stride) {
    float4 v = reinterpret_cast<const float4*>(x)[i];
    ushort4 h;
    h.x = f2h(v.x); h.y = f2h(v.y); h.z = f2h(v.z); h.w = f2h(v.w);
    reinterpret_cast<ushort4*>(o)[i] = h;
  }
}

// ---------- transpose X fp32 [b][s][h] -> XT fp16 [b][h][s] ----------
__global__ void transpose_f32_kernel(const float* __restrict__ x,
                                     u16* __restrict__ xt) {
  __shared__ u16 t[64][65];
  int b = blockIdx.z, s0 = blockIdx.x * 64, h0 = blockIdx.y * 64;
  int tx = threadIdx.x, ty = threadIdx.y;
  const float* src = x + ((size_t)b * S_ + s0) * H_ + h0;
#pragma unroll
  for (int i = 0; i < 4; ++i)
    t[ty + 16 * i][tx] = f2h(src[(size_t)(ty + 16 * i) * H_ + tx]);
  __syncthreads();
  u16* dst = xt + ((size_t)b * H_ + h0) * S_ + s0;
#pragma unroll
  for (int i = 0; i < 4; ++i)
    dst[(size_t)(ty + 16 * i) * S_ + tx] = t[tx][ty + 16 * i];
}

// ---------- async global->LDS 16B ----------
__device__ __forceinline__ void async_stage16(const u16* g, u16* l) {
  __builtin_amdgcn_global_load_lds(
      (__attribute__((address_space(1))) void*)g,
      (__attribute__((address_space(3))) void*)l, 16, 0, 0);
}

// ---------- 256x256x64 8-phase fp16 BT-GEMM ------------------------------
// C[m,n] = sum_k A[m,k]*B[n,k], A/B row-major k-contiguous fp16.
// 512 thr / 8 waves (2M x 4N); per-wave 128x64 out, frags interleaved so
// quadrant (qm,qn) <-> (A-half qm, B-half qn) for EVERY wave.
// LDS: 2 slots x (A 256x64 + B 256x64) = 128 KB, XOR-swizzle byte^((row&7)<<4)
// applied on staging source + fragment reads (proven 0-conflict in r3).
// Schedule per iter (2 K-tiles): 8 phases, stage 1 half/phase into the
// other slot, counted vmcnt placed BEFORE the closing barrier so all waves'
// loads are retired before any wave's dependent ds_read.
template <int OM>  // 0: fp32 out; 1: fp16 out + bias
__global__ __launch_bounds__(512) void gemm8_kernel(
    const u16* __restrict__ A, const u16* __restrict__ B,
    float* __restrict__ Cf, u16* __restrict__ Ch,
    const float* __restrict__ bias,
    int lda, int ldb, int ldc, int K,
    long sAz, long sBz, long sCz) {
  __shared__ __align__(16) u16 sA[2][256 * 64];
  __shared__ __align__(16) u16 sB[2][256 * 64];

  int tid = threadIdx.x, wave = tid >> 6, lane = tid & 63;
  int wm = wave >> 2, wn = wave & 3;
  int bm = blockIdx.x * 256, bn = blockIdx.y * 256;
  long zA = (long)blockIdx.z * sAz;
  long zB = (long)blockIdx.z * sBz;
  long zC = (long)blockIdx.z * sCz;
  const u16* gA = A + zA + (size_t)bm * lda;
  const u16* gB = B + zB + (size_t)bn * ldb;

  // staging constants: thread -> (row srow/srow+64, byte col scolb) of a half
  int srow = tid >> 3;             // 0..63
  int scolb = (tid & 7) << 4;      // 0..112
  int sco = (scolb ^ ((srow & 7) << 4)) >> 1;  // swizzled src col (u16)
  size_t aO0 = (size_t)srow * lda + sco, aO1 = aO0 + (size_t)64 * lda;
  size_t bO0 = (size_t)srow * ldb + sco, bO1 = bO0 + (size_t)64 * ldb;
  int ld0 = srow * 64 + (scolb >> 1), ld1 = ld0 + 64 * 64;

  auto stgA = [&](int slot, int half, int kofs) {
    const u16* g = gA + (size_t)(half * 128) * lda + kofs;
    u16* l = &sA[slot][half * 8192];
    async_stage16(g + aO0, l + ld0);
    async_stage16(g + aO1, l + ld1);
  };
  auto stgB = [&](int slot, int half, int kofs) {
    const u16* g = gB + (size_t)(half * 128) * ldb + kofs;
    u16* l = &sB[slot][half * 8192];
    async_stage16(g + bO0, l + ld0);
    async_stage16(g + bO1, l + ld1);
  };

  // fragment reads (swizzled)
  int la = lane & 15;
  int kg = (lane >> 4) << 4;
  auto frag = [&](const u16* base, int row, int colb) -> f16x8 {
    int off = (row << 7) + (colb ^ ((row & 7) << 4));
    return *reinterpret_cast<const f16x8*>(
        reinterpret_cast<const char*>(base) + off);
  };

  f16x8 aF[4][2], bF[2][2];
  f32x4 acc[8][4] = {};

  auto RA = [&](int slot, int qm) {
#pragma unroll
    for (int j = 0; j < 4; ++j)
#pragma unroll
      for (int ks = 0; ks < 2; ++ks)
        aF[j][ks] = frag(sA[slot], qm * 128 + (j * 2 + wm) * 16 + la,
                         ks * 64 + kg);
  };
  auto RB = [&](int slot, int qn) {
#pragma unroll
    for (int i = 0; i < 2; ++i)
#pragma unroll
      for (int ks = 0; ks < 2; ++ks)
        bF[i][ks] = frag(sB[slot], qn * 128 + (i * 4 + wn) * 16 + la,
                         ks * 64 + kg);
  };
  auto MM = [&](int qm, int qn) {
#pragma unroll
    for (int ks = 0; ks < 2; ++ks)
#pragma unroll
      for (int j = 0; j < 4; ++j)
#pragma unroll
        for (int i = 0; i < 2; ++i)
          acc[qm * 4 + j][qn * 2 + i] = __builtin_amdgcn_mfma_f32_16x16x32_f16(
              aF[j][ks], bF[i][ks], acc[qm * 4 + j][qn * 2 + i], 0, 0, 0);
  };

#define VM4 asm volatile("s_waitcnt vmcnt(4)" ::: "memory")
#define VM2 asm volatile("s_waitcnt vmcnt(2)" ::: "memory")
#define BAR __builtin_amdgcn_s_barrier()
#define LG0                                              \
  asm volatile("s_waitcnt lgkmcnt(0)" ::: "memory");     \
  __builtin_amdgcn_sched_barrier(0)
#define MFMA_CL(qm, qn)                 \
  __builtin_amdgcn_s_setprio(1);        \
  MM(qm, qn);                           \
  __builtin_amdgcn_s_setprio(0)

  // prologue: tile0 -> slot0 (A0,B0,A1,B1)
  stgA(0, 0, 0); stgB(0, 0, 0); stgA(0, 1, 0); stgB(0, 1, 0);
  VM4;   // retire A0,B0 (own); barrier makes it global
  BAR;

  int NI = K >> 7;  // iterations of 2 K-tiles
  for (int it = 0; it < NI; ++it) {
    int k1 = (2 * it + 1) << 6, k2 = (2 * it + 2) << 6;
    bool more = (it + 1 < NI);
    // ph1: q(0,0) slot0; stage A-half0 tile(2it+1)->slot1
    RA(0, 0); RB(0, 0); stgA(1, 0, k1);
    BAR; LG0; MFMA_CL(0, 0); VM2; BAR;
    // ph2: q(1,0); stage B-half0
    RA(0, 1); stgB(1, 0, k1);
    BAR; LG0; MFMA_CL(1, 0); BAR;
    // ph3: q(1,1); stage A-half1
    RB(0, 1); stgA(1, 1, k1);
    BAR; LG0; MFMA_CL(1, 1); BAR;
    // ph4: q(0,1); stage B-half1
    RA(0, 0); stgB(1, 1, k1);
    BAR; LG0; MFMA_CL(0, 1); VM4; BAR;
    // ph5: q(0,0) slot1; stage A-half0 tile(2it+2)->slot0
    RA(1, 0); RB(1, 0); if (more) stgA(0, 0, k2);
    BAR; LG0; MFMA_CL(0, 0); VM2; BAR;
    // ph6: q(1,0); stage B-half0
    RA(1, 1); if (more) stgB(0, 0, k2);
    BAR; LG0; MFMA_CL(1, 0); BAR;
    // ph7: q(1,1); stage A-half1
    RB(1, 1); if (more) stgA(0, 1, k2);
    BAR; LG0; MFMA_CL(1, 1); BAR;
    // ph8: q(0,1); stage B-half1
    RA(1, 0); if (more) stgB(0, 1, k2);
    BAR; LG0; MFMA_CL(0, 1); VM4; BAR;
  }
#undef VM4
#undef VM2
#undef BAR
#undef LG0
#undef MFMA_CL

  // Epilogue. C/D layout: col = lane&15, row = (lane>>4)*4 + reg.
#pragma unroll
  for (int mf = 0; mf < 8; ++mf) {
    int qm = mf >> 2, j = mf & 3;
    int row = bm + qm * 128 + (j * 2 + wm) * 16 + (lane >> 4) * 4;
#pragma unroll
    for (int nf = 0; nf < 4; ++nf) {
      int qn = nf >> 1, i = nf & 1;
      int col = bn + qn * 128 + (i * 4 + wn) * 16 + la;
#pragma unroll
      for (int r = 0; r < 4; ++r) {
        float v = acc[mf][nf][r];
        if constexpr (OM == 1) {
          Ch[zC + (size_t)(row + r) * ldc + col] = f2h(v + bias[col]);
        } else {
          Cf[zC + (size_t)(row + r) * ldc + col] = v;
        }
      }
    }
  }
}

// ---------- row softmax: fp32 [rows][2048] -> fp16 (pitch opitch u16) -----
__global__ __launch_bounds__(256) void softmax_kernel(const float* __restrict__ sc,
                                                      u16* __restrict__ attn,
                                                      int opitch) {
  __shared__ float red[4];
  size_t row = blockIdx.x;
  const float* p = sc + row * S_;
  u16* o = attn + row * (size_t)opitch;
  int t = threadIdx.x;
  float4 v0 = reinterpret_cast<const float4*>(p)[t];
  float4 v1 = reinterpret_cast<const float4*>(p)[t + 256];
  float mx = fmaxf(fmaxf(fmaxf(v0.x, v0.y), fmaxf(v0.z, v0.w)),
                   fmaxf(fmaxf(v1.x, v1.y), fmaxf(v1.z, v1.w)));
#pragma unroll
  for (int d = 32; d > 0; d >>= 1) mx = fmaxf(mx, __shfl_xor(mx, d));
  if ((t & 63) == 0) red[t >> 6] = mx;
  __syncthreads();
  mx = fmaxf(fmaxf(red[0], red[1]), fmaxf(red[2], red[3]));
  float e[8];
  e[0] = __expf(v0.x - mx); e[1] = __expf(v0.y - mx);
  e[2] = __expf(v0.z - mx); e[3] = __expf(v0.w - mx);
  e[4] = __expf(v1.x - mx); e[5] = __expf(v1.y - mx);
  e[6] = __expf(v1.z - mx); e[7] = __expf(v1.w - mx);
  float s = ((e[0] + e[1]) + (e[2] + e[3])) + ((e[4] + e[5]) + (e[6] + e[7]));
#pragma unroll
  for (int d = 32; d > 0; d >>= 1) s += __shfl_xor(s, d);
  __syncthreads();  // everyone done reading red (max phase)
  if ((t & 63) == 0) red[t >> 6] = s;
  __syncthreads();
  s = (red[0] + red[1]) + (red[2] + red[3]);
  float inv = 1.0f / s;
  ushort4 h0, h1;
  h0.x = f2h(e[0] * inv); h0.y = f2h(e[1] * inv);
  h0.z = f2h(e[2] * inv); h0.w = f2h(e[3] * inv);
  h1.x = f2h(e[4] * inv); h1.y = f2h(e[5] * inv);
  h1.z = f2h(e[6] * inv); h1.w = f2h(e[7] * inv);
  // all reads happened before the barriers above -> in-place safe
  reinterpret_cast<ushort4*>(o)[t] = h0;
  reinterpret_cast<ushort4*>(o)[t + 256] = h1;
}

extern "C" void kernel_launch(void* const* d_in, const int* in_sizes, int n_in,
                              void* d_out, int out_size, void* d_ws, size_t ws_size,
                              hipStream_t stream) {
  const float* X = (const float*)d_in[0];     // [8,2048,1024] fp32
  const float* W = (const float*)d_in[1];     // [1024,1024] fp32 (out,in)
  const float* bias = (const float*)d_in[2];  // [1024] fp32
  float* out = (float*)d_out;
  char* ws = (char*)d_ws;

  const size_t MB = 1ull << 20;
  u16* XF = (u16*)(ws);               // 32MB [16384][1024] fp16
  u16* WF = (u16*)(ws + 32 * MB);     // 2MB
  u16* XT = (u16*)(ws + 34 * MB);     // 32MB [b][1024][2048] fp16
  u16* QW = (u16*)(ws + 66 * MB);     // 32MB [16384][1024] fp16
  float* SC = (float*)(ws + 98 * MB); // CB*16MB fp32 scores
  u16* PF = (u16*)(ws + 162 * MB);    // 64MB full P (plan 2 only)

  // plan 2: CB=4 scores + dedicated full P, single full-GPU PV   (>=226MB)
  // plan 1: CB=4 scores + in-place P, PV per chunk               (>=163MB)
  // plan 0: CB=2 everything, in-place P                          (fallback)
  int plan = (ws_size >= 226 * MB) ? 2 : (ws_size >= 163 * MB) ? 1 : 0;
  int CB = (plan >= 1) ? 4 : 2;
  int nch = B_ / CB;

  // 1) X, W -> fp16
  f32_to_f16_kernel<<<2048, 256, 0, stream>>>(X, XF, M_ * H_ / 4);
  f32_to_f16_kernel<<<1024, 256, 0, stream>>>(W, WF, H_ * H_ / 4);
  // 2) XT[b][h][s] = fp16(X[b][s][h])
  transpose_f32_kernel<<<dim3(S_ / 64, H_ / 64, B_), dim3(64, 16), 0, stream>>>(X, XT);
  // 3) QW = X @ W^T + b -> fp16   (grid 64x4 = 256 blocks)
  gemm8_kernel<1><<<dim3(M_ / 256, H_ / 256, 1), 512, 0, stream>>>(
      XF, WF, nullptr, QW, bias, H_, H_, H_, H_, 0, 0, 0);
  // 4-6) per chunk: score -> softmax -> (PV)
  for (int ch = 0; ch < nch; ++ch) {
    long off = (long)ch * CB;
    gemm8_kernel<0><<<dim3(S_ / 256, S_ / 256, CB), 512, 0, stream>>>(
        QW + off * S_ * H_, XF + off * S_ * H_, SC, nullptr, nullptr,
        H_, H_, S_, H_, (long)S_ * H_, (long)S_ * H_, (long)S_ * S_);
    if (plan == 2) {
      softmax_kernel<<<CB * S_, 256, 0, stream>>>(
          SC, PF + off * S_ * S_, S_);
    } else {
      softmax_kernel<<<CB * S_, 256, 0, stream>>>(
          SC, (u16*)SC, 2 * S_);
      gemm8_kernel<0><<<dim3(S_ / 256, H_ / 256, CB), 512, 0, stream>>>(
          (u16*)SC, XT + off * (long)H_ * S_,
          out + off * (long)S_ * H_, nullptr, nullptr,
          2 * S_, S_, H_, S_, (long)S_ * 2 * S_, (long)H_ * S_, (long)S_ * H_);
    }
  }
  if (plan == 2) {
    // single full-GPU PV: grid 8x4x8 = 256 blocks
    gemm8_kernel<0><<<dim3(S_ / 256, H_ / 256, B_), 512, 0, stream>>>(
        PF, XT, out, nullptr, nullptr,
        S_, S_, H_, S_, (long)S_ * S_, (long)H_ * S_, (long)S_ * H_);
  }
}